// Round 1
// baseline (654.858 us; speedup 1.0000x reference)
//
#include <hip/hip_runtime.h>
#include <math.h>

#define SEQ 2048
#define DIM 1024
#define NH 16

typedef short s8v __attribute__((ext_vector_type(8)));
typedef float f4v __attribute__((ext_vector_type(4)));

__device__ __forceinline__ unsigned short f2bf(float x) {   // RNE
    unsigned u = __float_as_uint(x);
    u += 0x7FFFu + ((u >> 16) & 1u);
    return (unsigned short)(u >> 16);
}
__device__ __forceinline__ unsigned cvt_pk_bf16(float lo, float hi) {
    unsigned r;
    asm("v_cvt_pk_bf16_f32 %0, %1, %2" : "=v"(r) : "v"(lo), "v"(hi));
    return r;
}

// ---------------- q,k,v fp32 -> bf16 (one launch) ----------------
__global__ void conv3_f32_bf16(const float* __restrict__ q, const float* __restrict__ k,
                               const float* __restrict__ v,
                               unsigned short* __restrict__ qb, unsigned short* __restrict__ kb,
                               unsigned short* __restrict__ vb, int n4) {
    const float* in = (blockIdx.y == 0) ? q : (blockIdx.y == 1) ? k : v;
    unsigned short* out = (blockIdx.y == 0) ? qb : (blockIdx.y == 1) ? kb : vb;
    int i = blockIdx.x * 256 + threadIdx.x;
    if (i >= n4) return;
    float4 x = ((const float4*)in)[i];
    ushort4 o;
    o.x = f2bf(x.x); o.y = f2bf(x.y); o.z = f2bf(x.z); o.w = f2bf(x.w);
    ((ushort4*)out)[i] = o;
}

// ---------------- 4x W[K,N] fp32 -> WT[N,K] bf16 (one launch) ----------------
__global__ __launch_bounds__(256)
void convT4_f32_bf16(const float* __restrict__ W0, const float* __restrict__ W1,
                     const float* __restrict__ W2, const float* __restrict__ W3,
                     unsigned short* __restrict__ T0, unsigned short* __restrict__ T1,
                     unsigned short* __restrict__ T2, unsigned short* __restrict__ T3) {
    const float* W = (blockIdx.z == 0) ? W0 : (blockIdx.z == 1) ? W1 : (blockIdx.z == 2) ? W2 : W3;
    unsigned short* WT = (blockIdx.z == 0) ? T0 : (blockIdx.z == 1) ? T1 : (blockIdx.z == 2) ? T2 : T3;
    __shared__ float T[64][65];
    const int t = threadIdx.x;
    const int n0 = blockIdx.x * 64, k0 = blockIdx.y * 64;
    #pragma unroll
    for (int i = 0; i < 4; i++) {
        int idx = t + i * 256;
        int r = idx >> 4, c4 = idx & 15;
        float4 v = *(const float4*)&W[(size_t)(k0 + r) * DIM + n0 + c4 * 4];
        T[r][c4 * 4 + 0] = v.x; T[r][c4 * 4 + 1] = v.y;
        T[r][c4 * 4 + 2] = v.z; T[r][c4 * 4 + 3] = v.w;
    }
    __syncthreads();
    #pragma unroll
    for (int i = 0; i < 4; i++) {
        int idx = t + i * 256;
        int rn = idx >> 4, c4 = idx & 15;
        ushort4 o;
        o.x = f2bf(T[c4 * 4 + 0][rn]);
        o.y = f2bf(T[c4 * 4 + 1][rn]);
        o.z = f2bf(T[c4 * 4 + 2][rn]);
        o.w = f2bf(T[c4 * 4 + 3][rn]);
        *(ushort4*)&WT[(size_t)(n0 + rn) * DIM + k0 + c4 * 4] = o;
    }
}

// ---------------- GEMM core (m97 staging), shared by qkv+out projections ----------
// C = A[M,K]*BT[N,K]^T + bias. 128x128 tile, BK=64, global_load_lds staging.
template<int MODE>   // 0: fp32 out [M,DIM]; 1: bf16 head-split [B,NH,SEQ,64] * scale
__device__ __forceinline__
void gemm_core(const unsigned short* __restrict__ A,
               const unsigned short* __restrict__ BT,
               const float* __restrict__ bias, void* __restrict__ outp,
               float scale, int bx, int by)
{
    __shared__ __align__(16) unsigned short As[128 * 64];
    __shared__ __align__(16) unsigned short Bs[128 * 64];
    const int t = threadIdx.x;
    const int lane = t & 63, w = t >> 6;
    const int l15 = lane & 15, quad = lane >> 4;
    const int bm = by * 128, bn = bx * 128;
    const int wm = (w & 1) * 64, wn = (w >> 1) * 64;
    const int lrow = lane >> 3, lcol = (lane & 7) * 8;

    f4v acc[4][4];
    #pragma unroll
    for (int mi = 0; mi < 4; mi++)
        #pragma unroll
        for (int ni = 0; ni < 4; ni++)
            acc[mi][ni] = (f4v){0.f, 0.f, 0.f, 0.f};

    for (int k0 = 0; k0 < DIM; k0 += 64) {
        __syncthreads();
        #pragma unroll
        for (int i = 0; i < 4; i++) {
            int ci = w + i * 4;
            int row = ci * 8 + lrow;
            __builtin_amdgcn_global_load_lds(
                (const __attribute__((address_space(1))) unsigned int*)
                    (A + (size_t)(bm + row) * DIM + k0 + lcol),
                (__attribute__((address_space(3))) unsigned int*)(As + ci * 8 * 64),
                16, 0, 0);
            __builtin_amdgcn_global_load_lds(
                (const __attribute__((address_space(1))) unsigned int*)
                    (BT + (size_t)(bn + row) * DIM + k0 + lcol),
                (__attribute__((address_space(3))) unsigned int*)(Bs + ci * 8 * 64),
                16, 0, 0);
        }
        __syncthreads();
        #pragma unroll
        for (int kc = 0; kc < 2; kc++) {
            const int ko = kc * 32 + quad * 8;
            s8v af[4], bf[4];
            #pragma unroll
            for (int mi = 0; mi < 4; mi++)
                af[mi] = *(const s8v*)&As[(wm + mi * 16 + l15) * 64 + ko];
            #pragma unroll
            for (int ni = 0; ni < 4; ni++)
                bf[ni] = *(const s8v*)&Bs[(wn + ni * 16 + l15) * 64 + ko];
            #pragma unroll
            for (int mi = 0; mi < 4; mi++)
                #pragma unroll
                for (int ni = 0; ni < 4; ni++)
                    acc[mi][ni] = __builtin_amdgcn_mfma_f32_16x16x32_bf16(
                        af[mi], bf[ni], acc[mi][ni], 0, 0, 0);
        }
    }

    #pragma unroll
    for (int mi = 0; mi < 4; mi++) {
        #pragma unroll
        for (int ni = 0; ni < 4; ni++) {
            #pragma unroll
            for (int r = 0; r < 4; r++) {
                int m = bm + wm + mi * 16 + quad * 4 + r;
                int n = bn + wn + ni * 16 + l15;
                float val = acc[mi][ni][r] + bias[n];
                if (MODE == 0) {
                    ((float*)outp)[(size_t)m * DIM + n] = val;
                } else {
                    val *= scale;
                    int b = m >> 11, s = m & (SEQ - 1);
                    int h = n >> 6, dk = n & 63;
                    ((unsigned short*)outp)[(((size_t)(b * NH + h)) * SEQ + s) * 64 + dk] = f2bf(val);
                }
            }
        }
    }
}

// 3 projection GEMMs in one launch (z selects q/k/v)
__global__ __launch_bounds__(256)
void qkv_gemm(const unsigned short* __restrict__ qb, const unsigned short* __restrict__ kb,
              const unsigned short* __restrict__ vb,
              const unsigned short* __restrict__ WqT, const unsigned short* __restrict__ WkT,
              const unsigned short* __restrict__ WvT,
              const float* __restrict__ bq, const float* __restrict__ bk,
              const float* __restrict__ bv,
              unsigned short* __restrict__ qp, unsigned short* __restrict__ kp,
              unsigned short* __restrict__ vp)
{
    const int z = blockIdx.z;
    const unsigned short* A  = (z == 0) ? qb : (z == 1) ? kb : vb;
    const unsigned short* BT = (z == 0) ? WqT : (z == 1) ? WkT : WvT;
    const float* bias        = (z == 0) ? bq : (z == 1) ? bk : bv;
    unsigned short* outp     = (z == 0) ? qp : (z == 1) ? kp : vp;
    // fold 1/sqrt(64) AND log2(e) into Q so attention can use bare v_exp_f32 (exp2)
    float scale = (z == 0) ? 0.18033688011112042f : 1.0f;
    gemm_core<1>(A, BT, bias, outp, scale, blockIdx.x, blockIdx.y);
}

__global__ __launch_bounds__(256)
void out_gemm(const unsigned short* __restrict__ A, const unsigned short* __restrict__ BT,
              const float* __restrict__ bias, float* __restrict__ outp)
{
    gemm_core<0>(A, BT, bias, outp, 1.0f, blockIdx.x, blockIdx.y);
}

// ---------------- vp [bh][s][d] -> vpT [bh][d][s] ----------------
__global__ __launch_bounds__(256)
void transp_v(const unsigned short* __restrict__ vp, unsigned short* __restrict__ vpT) {
    __shared__ unsigned short T[64 * 72];
    const int t = threadIdx.x;
    const int bh = blockIdx.y, s0 = blockIdx.x * 64;
    const int r = t >> 3, c = (t & 7) * 8;
    #pragma unroll
    for (int i = 0; i < 2; i++) {
        int row = r + i * 32;
        *(s8v*)&T[row * 72 + c] = *(const s8v*)&vp[((size_t)bh * SEQ + s0 + row) * 64 + c];
    }
    __syncthreads();
    #pragma unroll
    for (int i = 0; i < 2; i++) {
        int d = r + i * 32;
        s8v o;
        #pragma unroll
        for (int j = 0; j < 8; j++) o[j] = (short)T[(c + j) * 72 + d];
        *(s8v*)&vpT[((size_t)bh * 64 + d) * SEQ + s0 + c] = o;
    }
}

// ---------------- MFMA flash attention v4 ----------------
// No K/V LDS staging: K/V tiles are L2-resident (512 KB per bh); MFMA fragments are
// read straight from global. Removes both per-tile barriers, the staging VALU, and
// the Ks/Vs bank conflicts. LDS holds only the per-wave P scratch (18.4 KB/block).
// S^T trick: QK^T computed as MFMA(A=K, B=Q); exp2 (log2e pre-folded into Q);
// P packed with v_cvt_pk_bf16_f32; softmax sum in-lane + deferred quad-reduce.
__global__ __launch_bounds__(256)
void attn_mfma(const unsigned short* __restrict__ Q,
               const unsigned short* __restrict__ Kp,
               const unsigned short* __restrict__ VT,
               unsigned short* __restrict__ AO)
{
    __shared__ __align__(16) unsigned short Ps[4][32 * 72];  // per-wave P [q][key]
    const int t = threadIdx.x;
    const int lane = t & 63, w = t >> 6;
    const int l15 = lane & 15, quad = lane >> 4;
    const int bh = blockIdx.y, q0 = blockIdx.x * 128;

    const unsigned short* qbase = Q + ((size_t)bh * SEQ + q0 + w * 32) * 64;
    // per-lane fragment bases: K[(kt*64 + mf*16 + l15)*64 + kc*32 + quad*8]
    const unsigned short* kfb = Kp + (size_t)bh * SEQ * 64 + (size_t)l15 * 64 + quad * 8;
    // V^T[(df*16 + l15)*SEQ + kt*64 + kc2*32 + quad*8]
    const unsigned short* vfb = VT + (size_t)bh * 64 * SEQ + (size_t)l15 * SEQ + quad * 8;

    // Q B-frags: B[n=l15 -> q=qs*16+l15][k=kc*32+quad*8+j -> d]
    s8v qf[2][2];
    #pragma unroll
    for (int qs = 0; qs < 2; qs++)
        #pragma unroll
        for (int kc = 0; kc < 2; kc++)
            qf[qs][kc] = *(const s8v*)&qbase[(qs * 16 + l15) * 64 + kc * 32 + quad * 8];

    f4v o_acc[2][4];   // [qs][df]
    #pragma unroll
    for (int qs = 0; qs < 2; qs++)
        #pragma unroll
        for (int df = 0; df < 4; df++) o_acc[qs][df] = (f4v){0.f, 0.f, 0.f, 0.f};
    float l_part[2] = {0.f, 0.f};

    unsigned short* Pw = (unsigned short*)Ps[w];

    for (int kt = 0; kt < 32; kt++) {
        // S^T = K*Q^T: A=kf (m=key), B=qf (n=q). Each kf read serves both q-slices.
        f4v s_acc[2][4];   // [qs][mf]: S^T[key=mf*16+quad*4+r][q=qs*16+l15]
        #pragma unroll
        for (int qs = 0; qs < 2; qs++)
            #pragma unroll
            for (int mf = 0; mf < 4; mf++) s_acc[qs][mf] = (f4v){0.f, 0.f, 0.f, 0.f};
        #pragma unroll
        for (int kc = 0; kc < 2; kc++) {
            #pragma unroll
            for (int mf = 0; mf < 4; mf++) {
                s8v kf = *(const s8v*)&kfb[(size_t)(kt * 64 + mf * 16) * 64 + kc * 32];
                #pragma unroll
                for (int qs = 0; qs < 2; qs++)
                    s_acc[qs][mf] = __builtin_amdgcn_mfma_f32_16x16x32_bf16(
                        kf, qf[qs][kc], s_acc[qs][mf], 0, 0, 0);
            }
        }

        // exp2 + in-lane partial sums; P packed via cvt_pk, stored as b64
        #pragma unroll
        for (int qs = 0; qs < 2; qs++) {
            #pragma unroll
            for (int mf = 0; mf < 4; mf++) {
                float p0 = exp2f(s_acc[qs][mf][0]);
                float p1 = exp2f(s_acc[qs][mf][1]);
                float p2 = exp2f(s_acc[qs][mf][2]);
                float p3 = exp2f(s_acc[qs][mf][3]);
                l_part[qs] += (p0 + p1) + (p2 + p3);
                uint2 pk;
                pk.x = cvt_pk_bf16(p0, p1);
                pk.y = cvt_pk_bf16(p2, p3);
                *(uint2*)&Pw[(qs * 16 + l15) * 72 + mf * 16 + quad * 4] = pk;
            }
        }

        // O += P*V (A=pf row-major [q][key], B=vf [d][key]); same-wave LDS ordered
        #pragma unroll
        for (int kc2 = 0; kc2 < 2; kc2++) {
            const int ko = kc2 * 32 + quad * 8;
            s8v pf0 = *(const s8v*)&Pw[(0 * 16 + l15) * 72 + ko];
            s8v pf1 = *(const s8v*)&Pw[(1 * 16 + l15) * 72 + ko];
            #pragma unroll
            for (int df = 0; df < 4; df++) {
                s8v vf = *(const s8v*)&vfb[(size_t)(df * 16) * SEQ + kt * 64 + kc2 * 32];
                o_acc[0][df] = __builtin_amdgcn_mfma_f32_16x16x32_bf16(pf0, vf, o_acc[0][df], 0, 0, 0);
                o_acc[1][df] = __builtin_amdgcn_mfma_f32_16x16x32_bf16(pf1, vf, o_acc[1][df], 0, 0, 0);
            }
        }
    }

    // deferred l reduction: sum over quads (keys partitioned by quad within lane)
    float lq[2][4];
    #pragma unroll
    for (int qs = 0; qs < 2; qs++) {
        float lt = l_part[qs];
        lt += __shfl_xor(lt, 16);
        lt += __shfl_xor(lt, 32);
        // lt now = full row sum for q = qs*16 + l15 (replicated across quads).
        // o_acc rows are q = quad*4+r: fetch via bpermute from lane (quad*4+r).
        #pragma unroll
        for (int r = 0; r < 4; r++)
            lq[qs][r] = 1.0f / __shfl(lt, quad * 4 + r);
    }

    const int b = bh >> 4, h = bh & (NH - 1);
    #pragma unroll
    for (int qs = 0; qs < 2; qs++) {
        #pragma unroll
        for (int r = 0; r < 4; r++) {
            int s = q0 + w * 32 + qs * 16 + quad * 4 + r;
            #pragma unroll
            for (int df = 0; df < 4; df++)
                AO[((size_t)(b * SEQ + s)) * DIM + h * 64 + df * 16 + l15] =
                    f2bf(o_acc[qs][df][r] * lq[qs][r]);
        }
    }
}

extern "C" void kernel_launch(void* const* d_in, const int* in_sizes, int n_in,
                              void* d_out, int out_size, void* d_ws, size_t ws_size,
                              hipStream_t stream) {
    const float* q  = (const float*)d_in[0];
    const float* k  = (const float*)d_in[1];
    const float* v  = (const float*)d_in[2];
    const float* Wq = (const float*)d_in[3];
    const float* bq = (const float*)d_in[4];
    const float* Wk = (const float*)d_in[5];
    const float* bk = (const float*)d_in[6];
    const float* Wv = (const float*)d_in[7];
    const float* bv = (const float*)d_in[8];
    const float* Wo = (const float*)d_in[9];
    const float* bo = (const float*)d_in[10];
    float* out = (float*)d_out;

    const size_t MK = (size_t)4 * SEQ * DIM;   // 8M elements
    const size_t WK = (size_t)DIM * DIM;
    unsigned short* wsu = (unsigned short*)d_ws;
    unsigned short* qb  = wsu;                 // dead after Q GEMM -> reused as vpT
    unsigned short* kb  = qb + MK;
    unsigned short* vb  = kb + MK;
    unsigned short* WqT = vb + MK;
    unsigned short* WkT = WqT + WK;
    unsigned short* WvT = WkT + WK;
    unsigned short* WoT = WvT + WK;
    unsigned short* qp  = WoT + WK;            // bf16 [64][2048][64], pre-scaled log2e/8
    unsigned short* kp  = qp + MK;
    unsigned short* vp  = kp + MK;
    unsigned short* ao  = vp + MK;
    unsigned short* vpT = qb;                  // alias: qb dead once GEMMs queued

    const int n4 = (int)(MK / 4);
    conv3_f32_bf16<<<dim3((n4 + 255) / 256, 3), 256, 0, stream>>>(q, k, v, qb, kb, vb, n4);
    convT4_f32_bf16<<<dim3(16, 16, 4), 256, 0, stream>>>(Wq, Wk, Wv, Wo, WqT, WkT, WvT, WoT);

    qkv_gemm<<<dim3(DIM / 128, (4 * SEQ) / 128, 3), 256, 0, stream>>>(
        qb, kb, vb, WqT, WkT, WvT, bq, bk, bv, qp, kp, vp);

    transp_v<<<dim3(SEQ / 64, 4 * NH), 256, 0, stream>>>(vp, vpT);

    attn_mfma<<<dim3(SEQ / 128, 4 * NH), 256, 0, stream>>>(qp, kp, vpT, ao);

    out_gemm<<<dim3(DIM / 128, (4 * SEQ) / 128), 256, 0, stream>>>(ao, WoT, bo, out);
}

// Round 2
// 379.080 us; speedup vs baseline: 1.7275x; 1.7275x over previous
//
#include <hip/hip_runtime.h>
#include <math.h>

#define SEQ 2048
#define DIM 1024
#define NH 16

typedef short s8v __attribute__((ext_vector_type(8)));
typedef float f4v __attribute__((ext_vector_type(4)));

__device__ __forceinline__ unsigned short f2bf(float x) {   // RNE
    unsigned u = __float_as_uint(x);
    u += 0x7FFFu + ((u >> 16) & 1u);
    return (unsigned short)(u >> 16);
}
__device__ __forceinline__ unsigned cvt_pk_bf16(float lo, float hi) {
    unsigned r;
    asm("v_cvt_pk_bf16_f32 %0, %1, %2" : "=v"(r) : "v"(lo), "v"(hi));
    return r;
}

// ---------------- q,k,v fp32 -> bf16 (one launch) ----------------
__global__ void conv3_f32_bf16(const float* __restrict__ q, const float* __restrict__ k,
                               const float* __restrict__ v,
                               unsigned short* __restrict__ qb, unsigned short* __restrict__ kb,
                               unsigned short* __restrict__ vb, int n4) {
    const float* in = (blockIdx.y == 0) ? q : (blockIdx.y == 1) ? k : v;
    unsigned short* out = (blockIdx.y == 0) ? qb : (blockIdx.y == 1) ? kb : vb;
    int i = blockIdx.x * 256 + threadIdx.x;
    if (i >= n4) return;
    float4 x = ((const float4*)in)[i];
    ushort4 o;
    o.x = f2bf(x.x); o.y = f2bf(x.y); o.z = f2bf(x.z); o.w = f2bf(x.w);
    ((ushort4*)out)[i] = o;
}

// ---------------- 4x W[K,N] fp32 -> WT[N,K] bf16 (one launch) ----------------
__global__ __launch_bounds__(256)
void convT4_f32_bf16(const float* __restrict__ W0, const float* __restrict__ W1,
                     const float* __restrict__ W2, const float* __restrict__ W3,
                     unsigned short* __restrict__ T0, unsigned short* __restrict__ T1,
                     unsigned short* __restrict__ T2, unsigned short* __restrict__ T3) {
    const float* W = (blockIdx.z == 0) ? W0 : (blockIdx.z == 1) ? W1 : (blockIdx.z == 2) ? W2 : W3;
    unsigned short* WT = (blockIdx.z == 0) ? T0 : (blockIdx.z == 1) ? T1 : (blockIdx.z == 2) ? T2 : T3;
    __shared__ float T[64][65];
    const int t = threadIdx.x;
    const int n0 = blockIdx.x * 64, k0 = blockIdx.y * 64;
    #pragma unroll
    for (int i = 0; i < 4; i++) {
        int idx = t + i * 256;
        int r = idx >> 4, c4 = idx & 15;
        float4 v = *(const float4*)&W[(size_t)(k0 + r) * DIM + n0 + c4 * 4];
        T[r][c4 * 4 + 0] = v.x; T[r][c4 * 4 + 1] = v.y;
        T[r][c4 * 4 + 2] = v.z; T[r][c4 * 4 + 3] = v.w;
    }
    __syncthreads();
    #pragma unroll
    for (int i = 0; i < 4; i++) {
        int idx = t + i * 256;
        int rn = idx >> 4, c4 = idx & 15;
        ushort4 o;
        o.x = f2bf(T[c4 * 4 + 0][rn]);
        o.y = f2bf(T[c4 * 4 + 1][rn]);
        o.z = f2bf(T[c4 * 4 + 2][rn]);
        o.w = f2bf(T[c4 * 4 + 3][rn]);
        *(ushort4*)&WT[(size_t)(n0 + rn) * DIM + k0 + c4 * 4] = o;
    }
}

// ---------------- GEMM core (m97 staging), shared by qkv+out projections ----------
// C = A[M,K]*BT[N,K]^T + bias. 128x128 tile, BK=64, global_load_lds staging.
template<int MODE>   // 0: fp32 out [M,DIM]; 1: bf16 head-split [B,NH,SEQ,64] * scale
__device__ __forceinline__
void gemm_core(const unsigned short* __restrict__ A,
               const unsigned short* __restrict__ BT,
               const float* __restrict__ bias, void* __restrict__ outp,
               float scale, int bx, int by)
{
    __shared__ __align__(16) unsigned short As[128 * 64];
    __shared__ __align__(16) unsigned short Bs[128 * 64];
    const int t = threadIdx.x;
    const int lane = t & 63, w = t >> 6;
    const int l15 = lane & 15, quad = lane >> 4;
    const int bm = by * 128, bn = bx * 128;
    const int wm = (w & 1) * 64, wn = (w >> 1) * 64;
    const int lrow = lane >> 3, lcol = (lane & 7) * 8;

    f4v acc[4][4];
    #pragma unroll
    for (int mi = 0; mi < 4; mi++)
        #pragma unroll
        for (int ni = 0; ni < 4; ni++)
            acc[mi][ni] = (f4v){0.f, 0.f, 0.f, 0.f};

    for (int k0 = 0; k0 < DIM; k0 += 64) {
        __syncthreads();
        #pragma unroll
        for (int i = 0; i < 4; i++) {
            int ci = w + i * 4;
            int row = ci * 8 + lrow;
            __builtin_amdgcn_global_load_lds(
                (const __attribute__((address_space(1))) unsigned int*)
                    (A + (size_t)(bm + row) * DIM + k0 + lcol),
                (__attribute__((address_space(3))) unsigned int*)(As + ci * 8 * 64),
                16, 0, 0);
            __builtin_amdgcn_global_load_lds(
                (const __attribute__((address_space(1))) unsigned int*)
                    (BT + (size_t)(bn + row) * DIM + k0 + lcol),
                (__attribute__((address_space(3))) unsigned int*)(Bs + ci * 8 * 64),
                16, 0, 0);
        }
        __syncthreads();
        #pragma unroll
        for (int kc = 0; kc < 2; kc++) {
            const int ko = kc * 32 + quad * 8;
            s8v af[4], bf[4];
            #pragma unroll
            for (int mi = 0; mi < 4; mi++)
                af[mi] = *(const s8v*)&As[(wm + mi * 16 + l15) * 64 + ko];
            #pragma unroll
            for (int ni = 0; ni < 4; ni++)
                bf[ni] = *(const s8v*)&Bs[(wn + ni * 16 + l15) * 64 + ko];
            #pragma unroll
            for (int mi = 0; mi < 4; mi++)
                #pragma unroll
                for (int ni = 0; ni < 4; ni++)
                    acc[mi][ni] = __builtin_amdgcn_mfma_f32_16x16x32_bf16(
                        af[mi], bf[ni], acc[mi][ni], 0, 0, 0);
        }
    }

    #pragma unroll
    for (int mi = 0; mi < 4; mi++) {
        #pragma unroll
        for (int ni = 0; ni < 4; ni++) {
            #pragma unroll
            for (int r = 0; r < 4; r++) {
                int m = bm + wm + mi * 16 + quad * 4 + r;
                int n = bn + wn + ni * 16 + l15;
                float val = acc[mi][ni][r] + bias[n];
                if (MODE == 0) {
                    ((float*)outp)[(size_t)m * DIM + n] = val;
                } else {
                    val *= scale;
                    int b = m >> 11, s = m & (SEQ - 1);
                    int h = n >> 6, dk = n & 63;
                    ((unsigned short*)outp)[(((size_t)(b * NH + h)) * SEQ + s) * 64 + dk] = f2bf(val);
                }
            }
        }
    }
}

// 3 projection GEMMs in one launch (z selects q/k/v)
__global__ __launch_bounds__(256)
void qkv_gemm(const unsigned short* __restrict__ qb, const unsigned short* __restrict__ kb,
              const unsigned short* __restrict__ vb,
              const unsigned short* __restrict__ WqT, const unsigned short* __restrict__ WkT,
              const unsigned short* __restrict__ WvT,
              const float* __restrict__ bq, const float* __restrict__ bk,
              const float* __restrict__ bv,
              unsigned short* __restrict__ qp, unsigned short* __restrict__ kp,
              unsigned short* __restrict__ vp)
{
    const int z = blockIdx.z;
    const unsigned short* A  = (z == 0) ? qb : (z == 1) ? kb : vb;
    const unsigned short* BT = (z == 0) ? WqT : (z == 1) ? WkT : WvT;
    const float* bias        = (z == 0) ? bq : (z == 1) ? bk : bv;
    unsigned short* outp     = (z == 0) ? qp : (z == 1) ? kp : vp;
    // fold 1/sqrt(64) AND log2(e) into Q so attention uses bare v_exp_f32 (exp2)
    float scale = (z == 0) ? 0.18033688011112042f : 1.0f;
    gemm_core<1>(A, BT, bias, outp, scale, blockIdx.x, blockIdx.y);
}

__global__ __launch_bounds__(256)
void out_gemm(const unsigned short* __restrict__ A, const unsigned short* __restrict__ BT,
              const float* __restrict__ bias, float* __restrict__ outp)
{
    gemm_core<0>(A, BT, bias, outp, 1.0f, blockIdx.x, blockIdx.y);
}

// ---------------- vp [bh][s][d] -> vpT [bh][d][s] ----------------
__global__ __launch_bounds__(256)
void transp_v(const unsigned short* __restrict__ vp, unsigned short* __restrict__ vpT) {
    __shared__ unsigned short T[64 * 72];
    const int t = threadIdx.x;
    const int bh = blockIdx.y, s0 = blockIdx.x * 64;
    const int r = t >> 3, c = (t & 7) * 8;
    #pragma unroll
    for (int i = 0; i < 2; i++) {
        int row = r + i * 32;
        *(s8v*)&T[row * 72 + c] = *(const s8v*)&vp[((size_t)bh * SEQ + s0 + row) * 64 + c];
    }
    __syncthreads();
    #pragma unroll
    for (int i = 0; i < 2; i++) {
        int d = r + i * 32;
        s8v o;
        #pragma unroll
        for (int j = 0; j < 8; j++) o[j] = (short)T[(c + j) * 72 + d];
        *(s8v*)&vpT[((size_t)bh * 64 + d) * SEQ + s0 + c] = o;
    }
}

// ---------------- MFMA flash attention v5 ----------------
// Staged (r0) structure + async-STAGE split (T14): next-tile K/V global loads are
// issued into registers at the top of the iteration (latency hidden under this
// tile's QK+softmax+PV), LDS writes happen after the post-PV barrier.
// exp2 with log2e pre-folded into Q; P packed via v_cvt_pk_bf16_f32; setprio(1)
// around MFMA clusters (T5, +4-7% on attn per m191).
__global__ __launch_bounds__(256)
void attn_mfma(const unsigned short* __restrict__ Q,
               const unsigned short* __restrict__ Kp,
               const unsigned short* __restrict__ VT,
               unsigned short* __restrict__ AO)
{
    __shared__ __align__(16) unsigned short Ks[64 * 72];     // [key][d]
    __shared__ __align__(16) unsigned short Vs[64 * 72];     // [d][key]
    __shared__ __align__(16) unsigned short Ps[4][32 * 72];  // per-wave P [q][key]
    const int t = threadIdx.x;
    const int lane = t & 63, w = t >> 6;
    const int l15 = lane & 15, quad = lane >> 4;
    const int bh = blockIdx.y, q0 = blockIdx.x * 128;

    const unsigned short* qbase = Q + ((size_t)bh * SEQ + q0 + w * 32) * 64;
    const unsigned short* kbase = Kp + (size_t)bh * SEQ * 64;
    const unsigned short* vtbase = VT + (size_t)bh * 64 * SEQ;

    // Q B-frags: B[n=l15 -> q=qs*16+l15][k=kc*32+quad*8+j -> d]
    s8v qf[2][2];
    #pragma unroll
    for (int qs = 0; qs < 2; qs++)
        #pragma unroll
        for (int kc = 0; kc < 2; kc++)
            qf[qs][kc] = *(const s8v*)&qbase[(qs * 16 + l15) * 64 + kc * 32 + quad * 8];

    f4v o_acc[2][4];   // [qs][df]
    #pragma unroll
    for (int qs = 0; qs < 2; qs++)
        #pragma unroll
        for (int df = 0; df < 4; df++) o_acc[qs][df] = (f4v){0.f, 0.f, 0.f, 0.f};
    float l_part[2] = {0.f, 0.f};

    const int srow = t >> 3, scol = (t & 7) * 8;
    unsigned short* Pw = (unsigned short*)Ps[w];

    // prologue: stage tile 0 (reg round-trip)
    s8v kreg[2], vreg[2];
    #pragma unroll
    for (int i = 0; i < 2; i++) {
        int row = srow + i * 32;
        kreg[i] = *(const s8v*)&kbase[(size_t)row * 64 + scol];
        vreg[i] = *(const s8v*)&vtbase[(size_t)row * SEQ + scol];
    }
    #pragma unroll
    for (int i = 0; i < 2; i++) {
        int row = srow + i * 32;
        *(s8v*)&Ks[row * 72 + scol] = kreg[i];
        *(s8v*)&Vs[row * 72 + scol] = vreg[i];
    }
    __syncthreads();

    for (int kt = 0; kt < 32; kt++) {
        // issue next-tile loads NOW; consumed by ds_write after the post-PV barrier.
        if (kt < 31) {
            #pragma unroll
            for (int i = 0; i < 2; i++) {
                int row = srow + i * 32;
                kreg[i] = *(const s8v*)&kbase[((size_t)((kt + 1) * 64 + row)) * 64 + scol];
                vreg[i] = *(const s8v*)&vtbase[(size_t)row * SEQ + (kt + 1) * 64 + scol];
            }
        }

        // S^T = K*Q^T: A=kf (m=key), B=qf (n=q). Each kf read serves both q-slices.
        f4v s_acc[2][4];   // [qs][mf]: S^T[key=mf*16+quad*4+r][q=qs*16+l15]
        #pragma unroll
        for (int qs = 0; qs < 2; qs++)
            #pragma unroll
            for (int mf = 0; mf < 4; mf++) s_acc[qs][mf] = (f4v){0.f, 0.f, 0.f, 0.f};
        __builtin_amdgcn_s_setprio(1);
        #pragma unroll
        for (int kc = 0; kc < 2; kc++) {
            const int ko = kc * 32 + quad * 8;
            #pragma unroll
            for (int mf = 0; mf < 4; mf++) {
                s8v kf = *(const s8v*)&Ks[(mf * 16 + l15) * 72 + ko];
                #pragma unroll
                for (int qs = 0; qs < 2; qs++)
                    s_acc[qs][mf] = __builtin_amdgcn_mfma_f32_16x16x32_bf16(
                        kf, qf[qs][kc], s_acc[qs][mf], 0, 0, 0);
            }
        }
        __builtin_amdgcn_s_setprio(0);

        // exp2 + in-lane partial sums; P packed via cvt_pk, stored as b64
        #pragma unroll
        for (int qs = 0; qs < 2; qs++) {
            #pragma unroll
            for (int mf = 0; mf < 4; mf++) {
                float p0 = __builtin_amdgcn_exp2f(s_acc[qs][mf][0]);
                float p1 = __builtin_amdgcn_exp2f(s_acc[qs][mf][1]);
                float p2 = __builtin_amdgcn_exp2f(s_acc[qs][mf][2]);
                float p3 = __builtin_amdgcn_exp2f(s_acc[qs][mf][3]);
                l_part[qs] += (p0 + p1) + (p2 + p3);
                uint2 pk;
                pk.x = cvt_pk_bf16(p0, p1);
                pk.y = cvt_pk_bf16(p2, p3);
                *(uint2*)&Pw[(qs * 16 + l15) * 72 + mf * 16 + quad * 4] = pk;
            }
        }

        // O += P*V (A=pf row-major [q][key], B=vf [d][key]); same-wave LDS ordered
        #pragma unroll
        for (int kc2 = 0; kc2 < 2; kc2++) {
            const int ko = kc2 * 32 + quad * 8;
            s8v pf0 = *(const s8v*)&Pw[(0 * 16 + l15) * 72 + ko];
            s8v pf1 = *(const s8v*)&Pw[(1 * 16 + l15) * 72 + ko];
            __builtin_amdgcn_s_setprio(1);
            #pragma unroll
            for (int df = 0; df < 4; df++) {
                s8v vf = *(const s8v*)&Vs[(df * 16 + l15) * 72 + ko];
                o_acc[0][df] = __builtin_amdgcn_mfma_f32_16x16x32_bf16(pf0, vf, o_acc[0][df], 0, 0, 0);
                o_acc[1][df] = __builtin_amdgcn_mfma_f32_16x16x32_bf16(pf1, vf, o_acc[1][df], 0, 0, 0);
            }
            __builtin_amdgcn_s_setprio(0);
        }

        __syncthreads();   // all Ks/Vs reads of this tile complete
        if (kt < 31) {
            #pragma unroll
            for (int i = 0; i < 2; i++) {
                int row = srow + i * 32;
                *(s8v*)&Ks[row * 72 + scol] = kreg[i];
                *(s8v*)&Vs[row * 72 + scol] = vreg[i];
            }
        }
        __syncthreads();   // next tile visible
    }

    // deferred l reduction: sum over quads (keys partitioned by quad within lane)
    float lq[2][4];
    #pragma unroll
    for (int qs = 0; qs < 2; qs++) {
        float lt = l_part[qs];
        lt += __shfl_xor(lt, 16);
        lt += __shfl_xor(lt, 32);
        // lt now = full row sum for q = qs*16 + l15 (replicated across quads).
        // o_acc rows are q = quad*4+r: fetch via bpermute from lane (quad*4+r).
        #pragma unroll
        for (int r = 0; r < 4; r++)
            lq[qs][r] = 1.0f / __shfl(lt, quad * 4 + r);
    }

    const int b = bh >> 4, h = bh & (NH - 1);
    #pragma unroll
    for (int qs = 0; qs < 2; qs++) {
        #pragma unroll
        for (int r = 0; r < 4; r++) {
            int s = q0 + w * 32 + qs * 16 + quad * 4 + r;
            #pragma unroll
            for (int df = 0; df < 4; df++)
                AO[((size_t)(b * SEQ + s)) * DIM + h * 64 + df * 16 + l15] =
                    f2bf(o_acc[qs][df][r] * lq[qs][r]);
        }
    }
}

extern "C" void kernel_launch(void* const* d_in, const int* in_sizes, int n_in,
                              void* d_out, int out_size, void* d_ws, size_t ws_size,
                              hipStream_t stream) {
    const float* q  = (const float*)d_in[0];
    const float* k  = (const float*)d_in[1];
    const float* v  = (const float*)d_in[2];
    const float* Wq = (const float*)d_in[3];
    const float* bq = (const float*)d_in[4];
    const float* Wk = (const float*)d_in[5];
    const float* bk = (const float*)d_in[6];
    const float* Wv = (const float*)d_in[7];
    const float* bv = (const float*)d_in[8];
    const float* Wo = (const float*)d_in[9];
    const float* bo = (const float*)d_in[10];
    float* out = (float*)d_out;

    const size_t MK = (size_t)4 * SEQ * DIM;   // 8M elements
    const size_t WK = (size_t)DIM * DIM;
    unsigned short* wsu = (unsigned short*)d_ws;
    unsigned short* qb  = wsu;                 // dead after Q GEMM -> reused as vpT
    unsigned short* kb  = qb + MK;
    unsigned short* vb  = kb + MK;
    unsigned short* WqT = vb + MK;
    unsigned short* WkT = WqT + WK;
    unsigned short* WvT = WkT + WK;
    unsigned short* WoT = WvT + WK;
    unsigned short* qp  = WoT + WK;            // bf16 [64][2048][64], pre-scaled log2e/8
    unsigned short* kp  = qp + MK;
    unsigned short* vp  = kp + MK;
    unsigned short* ao  = vp + MK;
    unsigned short* vpT = qb;                  // alias: qb dead once GEMMs queued

    const int n4 = (int)(MK / 4);
    conv3_f32_bf16<<<dim3((n4 + 255) / 256, 3), 256, 0, stream>>>(q, k, v, qb, kb, vb, n4);
    convT4_f32_bf16<<<dim3(16, 16, 4), 256, 0, stream>>>(Wq, Wk, Wv, Wo, WqT, WkT, WvT, WoT);

    qkv_gemm<<<dim3(DIM / 128, (4 * SEQ) / 128, 3), 256, 0, stream>>>(
        qb, kb, vb, WqT, WkT, WvT, bq, bk, bv, qp, kp, vp);

    transp_v<<<dim3(SEQ / 64, 4 * NH), 256, 0, stream>>>(vp, vpT);

    attn_mfma<<<dim3(SEQ / 128, 4 * NH), 256, 0, stream>>>(qp, kp, vpT, ao);

    out_gemm<<<dim3(DIM / 128, (4 * SEQ) / 128), 256, 0, stream>>>(ao, WoT, bo, out);
}